// Round 1
// baseline (2449.295 us; speedup 1.0000x reference)
//
#include <hip/hip_runtime.h>
#include <cstdint>
#include <cstddef>

#define TT 4
#define BB 8
#define CC 256
#define NN 1024
#define HEADS 8
#define DD 32

// Fused conv1x1 (GEMM over channels) + BatchNorm + LIF-over-time.
// Each thread computes outputs for one (b, o-pair, n-quad) across ALL T=4
// timesteps, so the sequential LIF recurrence runs in registers.
// fp64 accumulation to match a float64 numpy reference at spike decisions.
template<typename InT, typename OutT, bool HAS_BIAS, bool ADD_BASE>
__global__ __launch_bounds__(256) void conv_bn_lif(
    const float* __restrict__ W,      // [O, CIN]
    const float* __restrict__ bias,   // [O] or null
    const float* __restrict__ bn,     // [4, O] gamma,beta,mean,var
    const InT*   __restrict__ X,      // [T, B, CIN, N]
    OutT*        __restrict__ Out,    // [T, B, O, N]
    const float* __restrict__ base,   // [T, B, O, N] (ADD_BASE) or null
    int O, int CIN)
{
    __shared__ double Wsd[16][34];       // [kk][o_local], padded
    __shared__ double Xsd[TT][16][64];   // [t][kk][n_local]

    const int tid = threadIdx.x;
    const int tx = tid & 15;             // n lane
    const int ty = tid >> 4;             // o lane
    const int n0 = blockIdx.x * 64;
    const int o0 = blockIdx.y * 32;
    const int b  = blockIdx.z;

    double acc[TT][2][4];
#pragma unroll
    for (int t = 0; t < TT; ++t)
#pragma unroll
        for (int i = 0; i < 2; ++i)
#pragma unroll
            for (int j = 0; j < 4; ++j) acc[t][i][j] = 0.0;

    for (int c0 = 0; c0 < CIN; c0 += 16) {
        // stage W tile (32 o x 16 k) as double
        for (int i = tid; i < 512; i += 256) {
            int ol = i >> 4, kk = i & 15;
            Wsd[kk][ol] = (double)W[(size_t)(o0 + ol) * CIN + c0 + kk];
        }
        // stage X tiles for all 4 timesteps (4 x 16 k x 64 n) as double
        for (int i = tid; i < 4096; i += 256) {
            int nl = i & 63, kk = (i >> 6) & 15, t = i >> 10;
            Xsd[t][kk][nl] =
                (double)X[(((size_t)t * BB + b) * CIN + c0 + kk) * NN + n0 + nl];
        }
        __syncthreads();
#pragma unroll
        for (int kk = 0; kk < 16; ++kk) {
            double w0 = Wsd[kk][ty * 2];
            double w1 = Wsd[kk][ty * 2 + 1];
#pragma unroll
            for (int t = 0; t < TT; ++t) {
#pragma unroll
                for (int j = 0; j < 4; ++j) {
                    double xv = Xsd[t][kk][tx + j * 16];
                    acc[t][0][j] += w0 * xv;
                    acc[t][1][j] += w1 * xv;
                }
            }
        }
        __syncthreads();
    }

    // epilogue: bias + BN + LIF (tau=2, v_reset=0 hard reset, v_th=1)
#pragma unroll
    for (int i = 0; i < 2; ++i) {
        int o = o0 + ty * 2 + i;
        double g   = (double)bn[0 * O + o];
        double be  = (double)bn[1 * O + o];
        double mu  = (double)bn[2 * O + o];
        double var = (double)bn[3 * O + o];
        double scale = g / sqrt(var + 1e-5);
        double bi = 0.0;
        if constexpr (HAS_BIAS) bi = (double)bias[o];
#pragma unroll
        for (int j = 0; j < 4; ++j) {
            int n = n0 + tx + j * 16;
            double v = 0.0;
#pragma unroll
            for (int t = 0; t < TT; ++t) {
                double val = (acc[t][i][j] + bi - mu) * scale + be;
                v = v + (val - v) * 0.5;
                double s = (v >= 1.0) ? 1.0 : 0.0;
                size_t idx = (((size_t)t * BB + b) * O + o) * NN + n;
                if constexpr (ADD_BASE) {
                    Out[idx] = (OutT)((double)base[idx] + s);
                } else {
                    Out[idx] = (OutT)s;
                }
                v = v * (1.0 - s);
            }
        }
    }
}

// kv[t,b,h,d,e] = sum_n k[t,b,h*32+d,n] * v[t,b,h*32+e,n]
// spikes are 0/1 -> exact integer arithmetic in fp32.
__global__ __launch_bounds__(256) void kv_kernel(
    const float* __restrict__ k_s, const float* __restrict__ v_s,
    float* __restrict__ kv)
{
    const int blk = blockIdx.x;          // (t*BB+b)*HEADS + h
    const int h = blk & 7;
    const int m = blk >> 3;              // t*BB + b
    __shared__ float ks[32][65];
    __shared__ float vs[32][65];
    const int tid = threadIdx.x;
    const int d = tid >> 3;
    const int e0 = (tid & 7) * 4;
    float acc[4] = {0.f, 0.f, 0.f, 0.f};
    const size_t basek = ((size_t)m * CC + h * DD) * NN;
    for (int nc = 0; nc < NN; nc += 64) {
        for (int i = tid; i < 2048; i += 256) {
            int r = i >> 6, nl = i & 63;
            ks[r][nl] = k_s[basek + (size_t)r * NN + nc + nl];
            vs[r][nl] = v_s[basek + (size_t)r * NN + nc + nl];
        }
        __syncthreads();
        for (int nl = 0; nl < 64; ++nl) {
            float kd = ks[d][nl];
#pragma unroll
            for (int j = 0; j < 4; ++j) acc[j] += kd * vs[e0 + j][nl];
        }
        __syncthreads();
    }
#pragma unroll
    for (int j = 0; j < 4; ++j)
        kv[(size_t)blk * 1024 + d * 32 + e0 + j] = acc[j];
}

// a_pre[t,b,h*32+e,n] = 0.125 * sum_d q[t,b,h*32+d,n] * kv[t,b,h,d,e]
// then LIF over t with v_th = 0.5. Exact dyadic arithmetic in fp32.
__global__ __launch_bounds__(256) void attn_a_lif(
    const float* __restrict__ q_s, const float* __restrict__ kv,
    float* __restrict__ a_s)
{
    const int tid = threadIdx.x;
    const int n = blockIdx.x * 256 + tid;
    const int c = blockIdx.y;
    const int b = blockIdx.z;
    const int h = c >> 5;
    const int e = c & 31;
    __shared__ float kvs[TT][32];
    if (tid < 128) {
        int t = tid >> 5, d2 = tid & 31;
        kvs[t][d2] = kv[(((size_t)t * BB + b) * HEADS + h) * 1024 + d2 * 32 + e];
    }
    __syncthreads();
    float val[TT];
#pragma unroll
    for (int t = 0; t < TT; ++t) {
        float s = 0.f;
        const size_t qb = (((size_t)t * BB + b) * CC + h * DD) * NN + n;
#pragma unroll 8
        for (int d2 = 0; d2 < 32; ++d2)
            s += q_s[qb + (size_t)d2 * NN] * kvs[t][d2];
        val[t] = s * 0.125f;
    }
    float v = 0.f;
#pragma unroll
    for (int t = 0; t < TT; ++t) {
        v = v + (val[t] - v) * 0.5f;
        float s = (v >= 0.5f) ? 1.f : 0.f;
        a_s[(((size_t)t * BB + b) * CC + c) * NN + n] = s;
        v = v * (1.f - s);
    }
}

extern "C" void kernel_launch(void* const* d_in, const int* in_sizes, int n_in,
                              void* d_out, int out_size, void* d_ws, size_t ws_size,
                              hipStream_t stream)
{
    const float* x       = (const float*)d_in[0];
    const float* q_w     = (const float*)d_in[1];
    const float* q_bn    = (const float*)d_in[2];
    const float* k_w     = (const float*)d_in[3];
    const float* k_bn    = (const float*)d_in[4];
    const float* v_w     = (const float*)d_in[5];
    const float* v_bn    = (const float*)d_in[6];
    const float* proj_w  = (const float*)d_in[7];
    const float* proj_b  = (const float*)d_in[8];
    const float* proj_bn = (const float*)d_in[9];
    const float* mlp1_w  = (const float*)d_in[10];
    const float* mlp1_b  = (const float*)d_in[11];
    const float* mlp1_bn = (const float*)d_in[12];
    const float* mlp2_w  = (const float*)d_in[13];
    const float* mlp2_b  = (const float*)d_in[14];
    const float* mlp2_bn = (const float*)d_in[15];

    const size_t SZ = (size_t)TT * BB * CC * NN;   // 8388608 elements
    char* ws = (char*)d_ws;
    float*   q_s   = (float*)(ws);
    float*   k_s   = (float*)(ws + SZ * 4);
    float*   v_s   = (float*)(ws + 2 * SZ * 4);
    float*   a_s   = (float*)(ws + 3 * SZ * 4);
    float*   kvb   = (float*)(ws + 4 * SZ * 4);    // 262144 floats = 1 MB
    float*   x_new = (float*)(ws);                 // reuses q_s region
    uint8_t* h1    = (uint8_t*)(ws + SZ * 4);      // reuses k_s region (33.5 MB)

    dim3 blk(256);
    dim3 g256(16, 256 / 32, 8);    // n-tiles, o-tiles, b

    // Q/K/V conv + BN + LIF -> spike trains (f32 0/1)
    conv_bn_lif<float, float, false, false><<<g256, blk, 0, stream>>>(
        q_w, nullptr, q_bn, x, q_s, nullptr, 256, 256);
    conv_bn_lif<float, float, false, false><<<g256, blk, 0, stream>>>(
        k_w, nullptr, k_bn, x, k_s, nullptr, 256, 256);
    conv_bn_lif<float, float, false, false><<<g256, blk, 0, stream>>>(
        v_w, nullptr, v_bn, x, v_s, nullptr, 256, 256);

    // attention: kv = k^T v, then a = 0.125 * q kv -> LIF(0.5)
    kv_kernel<<<dim3(TT * BB * HEADS), blk, 0, stream>>>(k_s, v_s, kvb);
    attn_a_lif<<<dim3(4, 256, 8), blk, 0, stream>>>(q_s, kvb, a_s);

    // proj conv + bias + BN + LIF, fused residual: x_new = x + ssa
    conv_bn_lif<float, float, true, true><<<g256, blk, 0, stream>>>(
        proj_w, proj_b, proj_bn, a_s, x_new, x, 256, 256);

    // MLP: 256 -> 1024 (spikes as uint8) -> 256, fused residual to d_out
    conv_bn_lif<float, uint8_t, true, false><<<dim3(16, 1024 / 32, 8), blk, 0, stream>>>(
        mlp1_w, mlp1_b, mlp1_bn, x_new, h1, nullptr, 1024, 256);
    conv_bn_lif<uint8_t, float, true, true><<<g256, blk, 0, stream>>>(
        mlp2_w, mlp2_b, mlp2_bn, h1, (float*)d_out, x_new, 256, 1024);
}

// Round 3
// 1717.737 us; speedup vs baseline: 1.4259x; 1.4259x over previous
//
#include <hip/hip_runtime.h>
#include <cstdint>
#include <cstddef>

#define TT 4
#define BB 8
#define CC 256
#define NN 1024
#define HEADS 8
#define DD 32

typedef __attribute__((ext_vector_type(4))) double f64x4;

// Fused conv1x1 (GEMM) + BatchNorm + LIF-over-time using fp64 MFMA.
// Block: 64(o) x 64(n) output tile for ONE b, all T=4 timesteps.
// 4 waves; wave w computes the 32x32 sub-tile (osub=(w&1)*32, nsub=(w>>1)*32)
// for all 4 t's -> LIF recurrence runs in registers in the epilogue.
// The C/D (and A/B row) lane mapping of v_mfma_f64_16x16x4f64 is recovered at
// RUNTIME via two probe MFMAs (layout-agnostic): probe1 = A(=lane&15) x ones
// gives 4*row-source per (lane,reg); probe2 = ones x B(=lane&15) gives 4*col.
template<typename InT, typename OutT, bool HAS_BIAS, bool ADD_BASE>
__global__ __launch_bounds__(256) void conv_bn_lif_mfma(
    const float* __restrict__ W,      // [O, CIN]
    const float* __restrict__ bias,   // [O] or null
    const float* __restrict__ bn,     // [4, O] gamma,beta,mean,var
    const InT*   __restrict__ X,      // [T, B, CIN, N]
    OutT*        __restrict__ Out,    // [T, B, O, N]
    const float* __restrict__ base,   // [T, B, O, N] (ADD_BASE) or null
    int O, int CIN)
{
    __shared__ float Ws[64][36];        // stride 36 floats (144B, 16B-aligned rows)
    __shared__ float Xs[TT][32][68];    // stride 68 floats (272B, 16B-aligned rows)

    const int tid  = threadIdx.x;
    const int lane = tid & 63;
    const int wave = tid >> 6;
    const int col  = lane & 15;
    const int rowg = lane >> 4;         // 0..3  (k-group)
    const int osub = (wave & 1) * 32;
    const int nsub = (wave >> 1) * 32;
    const int n0 = blockIdx.x * 64;
    const int o0 = blockIdx.y * 64;
    const int b  = blockIdx.z;

    // ---- runtime layout probes (exact integer arithmetic in f64) ----
    f64x4 p1 = {0.0, 0.0, 0.0, 0.0};
    f64x4 p2 = {0.0, 0.0, 0.0, 0.0};
    const double lanev = (double)col;
    p1 = __builtin_amdgcn_mfma_f64_16x16x4f64(lanev, 1.0, p1, 0, 0, 0);
    p2 = __builtin_amdgcn_mfma_f64_16x16x4f64(1.0, lanev, p2, 0, 0, 0);
    int o_idx[4], n_idx[4];
#pragma unroll
    for (int r = 0; r < 4; ++r) {
        o_idx[r] = (int)(p1[r] * 0.25);   // which A-row (o within 16) reg r holds
        n_idx[r] = (int)(p2[r] * 0.25);   // which B-col (n within 16) reg r holds
    }

    f64x4 acc[TT][2][2];
#pragma unroll
    for (int t = 0; t < TT; ++t)
#pragma unroll
        for (int mf = 0; mf < 2; ++mf)
#pragma unroll
            for (int nf = 0; nf < 2; ++nf)
                acc[t][mf][nf] = (f64x4){0.0, 0.0, 0.0, 0.0};

    for (int c0 = 0; c0 < CIN; c0 += 32) {
        // stage W tile: 64 o x 32 k  (512 float4)
        for (int idx = tid; idx < 512; idx += 256) {
            int ol = idx >> 3, k4 = idx & 7;
            float4 wv = *reinterpret_cast<const float4*>(
                &W[(size_t)(o0 + ol) * CIN + c0 + k4 * 4]);
            *reinterpret_cast<float4*>(&Ws[ol][k4 * 4]) = wv;
        }
        // stage X tiles for 4 timesteps: 4 x 32 k x 64 n (2048 float4)
        for (int idx = tid; idx < 2048; idx += 256) {
            int t = idx >> 9, kk = (idx >> 4) & 31, n4 = idx & 15;
            const size_t goff =
                (((size_t)t * BB + b) * CIN + c0 + kk) * NN + n0 + n4 * 4;
            float4 xv;
            if constexpr (__is_same(InT, uint8_t)) {
                uchar4 u = *reinterpret_cast<const uchar4*>(&X[goff]);
                xv = make_float4((float)u.x, (float)u.y, (float)u.z, (float)u.w);
            } else {
                xv = *reinterpret_cast<const float4*>(&X[goff]);
            }
            *reinterpret_cast<float4*>(&Xs[t][kk][n4 * 4]) = xv;
        }
        __syncthreads();
#pragma unroll
        for (int k0 = 0; k0 < 32; k0 += 4) {
            double av[2];
#pragma unroll
            for (int mf = 0; mf < 2; ++mf)
                av[mf] = (double)Ws[osub + mf * 16 + col][k0 + rowg];
#pragma unroll
            for (int nf = 0; nf < 2; ++nf) {
#pragma unroll
                for (int t = 0; t < TT; ++t) {
                    double bv = (double)Xs[t][k0 + rowg][nsub + nf * 16 + col];
                    acc[t][0][nf] = __builtin_amdgcn_mfma_f64_16x16x4f64(
                        av[0], bv, acc[t][0][nf], 0, 0, 0);
                    acc[t][1][nf] = __builtin_amdgcn_mfma_f64_16x16x4f64(
                        av[1], bv, acc[t][1][nf], 0, 0, 0);
                }
            }
        }
        __syncthreads();
    }

    // epilogue: bias + BN + LIF (tau=2, hard reset, v_th=1), probe-indexed
#pragma unroll
    for (int mf = 0; mf < 2; ++mf) {
#pragma unroll
        for (int r = 0; r < 4; ++r) {
            const int o = o0 + osub + mf * 16 + o_idx[r];
            const double g   = (double)bn[0 * O + o];
            const double be  = (double)bn[1 * O + o];
            const double mu  = (double)bn[2 * O + o];
            const double var = (double)bn[3 * O + o];
            const double scale = g / sqrt(var + 1e-5);
            double bi = 0.0;
            if constexpr (HAS_BIAS) bi = (double)bias[o];
#pragma unroll
            for (int nf = 0; nf < 2; ++nf) {
                const int n = n0 + nsub + nf * 16 + n_idx[r];
                double v = 0.0;
#pragma unroll
                for (int t = 0; t < TT; ++t) {
                    double val = (acc[t][mf][nf][r] + bi - mu) * scale + be;
                    v = v + (val - v) * 0.5;
                    double s = (v >= 1.0) ? 1.0 : 0.0;
                    size_t idx = (((size_t)t * BB + b) * O + o) * NN + n;
                    if constexpr (ADD_BASE) {
                        Out[idx] = (OutT)((double)base[idx] + s);
                    } else {
                        Out[idx] = (OutT)s;
                    }
                    v = v * (1.0 - s);
                }
            }
        }
    }
}

// kv[t,b,h,d,e] = sum_n k[t,b,h*32+d,n] * v[t,b,h*32+e,n]  (exact int in fp32)
__global__ __launch_bounds__(256) void kv_kernel(
    const float* __restrict__ k_s, const float* __restrict__ v_s,
    float* __restrict__ kv)
{
    const int blk = blockIdx.x;          // (t*BB+b)*HEADS + h
    const int h = blk & 7;
    const int m = blk >> 3;              // t*BB + b
    __shared__ float ks[32][65];
    __shared__ float vs[32][65];
    const int tid = threadIdx.x;
    const int d = tid >> 3;
    const int e0 = (tid & 7) * 4;
    float acc[4] = {0.f, 0.f, 0.f, 0.f};
    const size_t basek = ((size_t)m * CC + h * DD) * NN;
    for (int nc = 0; nc < NN; nc += 64) {
        for (int i = tid; i < 2048; i += 256) {
            int r = i >> 6, nl = i & 63;
            ks[r][nl] = k_s[basek + (size_t)r * NN + nc + nl];
            vs[r][nl] = v_s[basek + (size_t)r * NN + nc + nl];
        }
        __syncthreads();
        for (int nl = 0; nl < 64; ++nl) {
            float kd = ks[d][nl];
#pragma unroll
            for (int j = 0; j < 4; ++j) acc[j] += kd * vs[e0 + j][nl];
        }
        __syncthreads();
    }
#pragma unroll
    for (int j = 0; j < 4; ++j)
        kv[(size_t)blk * 1024 + d * 32 + e0 + j] = acc[j];
}

// a = 0.125 * q @ kv -> LIF(v_th=0.5); exact dyadic arithmetic in fp32.
__global__ __launch_bounds__(256) void attn_a_lif(
    const float* __restrict__ q_s, const float* __restrict__ kv,
    float* __restrict__ a_s)
{
    const int tid = threadIdx.x;
    const int n = blockIdx.x * 256 + tid;
    const int c = blockIdx.y;
    const int b = blockIdx.z;
    const int h = c >> 5;
    const int e = c & 31;
    __shared__ float kvs[TT][32];
    if (tid < 128) {
        int t = tid >> 5, d2 = tid & 31;
        kvs[t][d2] = kv[(((size_t)t * BB + b) * HEADS + h) * 1024 + d2 * 32 + e];
    }
    __syncthreads();
    float val[TT];
#pragma unroll
    for (int t = 0; t < TT; ++t) {
        float s = 0.f;
        const size_t qb = (((size_t)t * BB + b) * CC + h * DD) * NN + n;
#pragma unroll 8
        for (int d2 = 0; d2 < 32; ++d2)
            s += q_s[qb + (size_t)d2 * NN] * kvs[t][d2];
        val[t] = s * 0.125f;
    }
    float v = 0.f;
#pragma unroll
    for (int t = 0; t < TT; ++t) {
        v = v + (val[t] - v) * 0.5f;
        float s = (v >= 0.5f) ? 1.f : 0.f;
        a_s[(((size_t)t * BB + b) * CC + c) * NN + n] = s;
        v = v * (1.f - s);
    }
}

extern "C" void kernel_launch(void* const* d_in, const int* in_sizes, int n_in,
                              void* d_out, int out_size, void* d_ws, size_t ws_size,
                              hipStream_t stream)
{
    const float* x       = (const float*)d_in[0];
    const float* q_w     = (const float*)d_in[1];
    const float* q_bn    = (const float*)d_in[2];
    const float* k_w     = (const float*)d_in[3];
    const float* k_bn    = (const float*)d_in[4];
    const float* v_w     = (const float*)d_in[5];
    const float* v_bn    = (const float*)d_in[6];
    const float* proj_w  = (const float*)d_in[7];
    const float* proj_b  = (const float*)d_in[8];
    const float* proj_bn = (const float*)d_in[9];
    const float* mlp1_w  = (const float*)d_in[10];
    const float* mlp1_b  = (const float*)d_in[11];
    const float* mlp1_bn = (const float*)d_in[12];
    const float* mlp2_w  = (const float*)d_in[13];
    const float* mlp2_b  = (const float*)d_in[14];
    const float* mlp2_bn = (const float*)d_in[15];

    const size_t SZ = (size_t)TT * BB * CC * NN;   // 8388608 elements
    char* ws = (char*)d_ws;
    float*   q_s   = (float*)(ws);
    float*   k_s   = (float*)(ws + SZ * 4);
    float*   v_s   = (float*)(ws + 2 * SZ * 4);
    float*   a_s   = (float*)(ws + 3 * SZ * 4);
    float*   kvb   = (float*)(ws + 4 * SZ * 4);    // 1 MB
    float*   x_new = (float*)(ws);                 // reuses q_s region
    uint8_t* h1    = (uint8_t*)(ws + SZ * 4);      // reuses k_s region (33.5 MB)

    dim3 blk(256);
    dim3 g256(NN / 64, 256 / 64, BB);   // (16, 4, 8)
    dim3 g1024(NN / 64, 1024 / 64, BB); // (16, 16, 8)

    // Q/K/V conv + BN + LIF -> spike trains (f32 0/1)
    conv_bn_lif_mfma<float, float, false, false><<<g256, blk, 0, stream>>>(
        q_w, nullptr, q_bn, x, q_s, nullptr, 256, 256);
    conv_bn_lif_mfma<float, float, false, false><<<g256, blk, 0, stream>>>(
        k_w, nullptr, k_bn, x, k_s, nullptr, 256, 256);
    conv_bn_lif_mfma<float, float, false, false><<<g256, blk, 0, stream>>>(
        v_w, nullptr, v_bn, x, v_s, nullptr, 256, 256);

    // attention: kv = k^T v, then a = 0.125 * q kv -> LIF(0.5)
    kv_kernel<<<dim3(TT * BB * HEADS), blk, 0, stream>>>(k_s, v_s, kvb);
    attn_a_lif<<<dim3(4, 256, 8), blk, 0, stream>>>(q_s, kvb, a_s);

    // proj conv + bias + BN + LIF, fused residual: x_new = x + ssa
    conv_bn_lif_mfma<float, float, true, true><<<g256, blk, 0, stream>>>(
        proj_w, proj_b, proj_bn, a_s, x_new, x, 256, 256);

    // MLP: 256 -> 1024 (spikes as uint8) -> 256, fused residual to d_out
    conv_bn_lif_mfma<float, uint8_t, true, false><<<g1024, blk, 0, stream>>>(
        mlp1_w, mlp1_b, mlp1_bn, x_new, h1, nullptr, 1024, 256);
    conv_bn_lif_mfma<uint8_t, float, true, true><<<g256, blk, 0, stream>>>(
        mlp2_w, mlp2_b, mlp2_bn, h1, (float*)d_out, x_new, 256, 1024);
}

// Round 4
// 1103.954 us; speedup vs baseline: 2.2187x; 1.5560x over previous
//
#include <hip/hip_runtime.h>
#include <cstdint>
#include <cstddef>

#define TT 4
#define BB 8
#define CC 256
#define NN 1024
#define HEADS 8
#define DD 32

typedef __attribute__((ext_vector_type(4))) double f64x4;

// Fused conv1x1 (GEMM) + BatchNorm + LIF-over-time using fp64 MFMA.
// Block: 32(o) x 32(n) tile, 4 waves; wave w computes timestep t=w.
// acc per wave = [2][2] f64x4 = 32 VGPRs -> 4 waves/SIMD occupancy.
// LIF runs in an LDS epilogue: waves dump f64 pre-activations (overlaying
// the X tile), then each thread LIFs its (o,n) across t=0..3.
// C/D lane mapping of v_mfma_f64_16x16x4f64 recovered at runtime via probes.
template<typename InT, typename OutT, bool HAS_BIAS, bool ADD_BASE>
__global__ __launch_bounds__(256, 4) void conv_bn_lif_mfma(
    const float* __restrict__ W,      // [O, CIN]
    const float* __restrict__ bias,   // [O] or null
    const float* __restrict__ bn,     // [4, O] gamma,beta,mean,var
    const InT*   __restrict__ X,      // [T, B, CIN, N]
    OutT*        __restrict__ Out,    // [T, B, O, N]
    const float* __restrict__ base,   // [T, B, O, N] (ADD_BASE) or null
    int O, int CIN)
{
    __shared__ float Ws[32][36];                      // 4608 B
    __shared__ __align__(16) float Xs[TT][32][68];    // 34816 B
    double* pre = (double*)&Xs[0][0][0];              // [4][32][32] f64 = 32768 B overlay

    const int tid  = threadIdx.x;
    const int lane = tid & 63;
    const int wave = tid >> 6;          // == timestep t for the GEMM phase
    const int col  = lane & 15;
    const int rowg = lane >> 4;         // 0..3  (k-group)
    const int n0 = blockIdx.x * 32;
    const int o0 = blockIdx.y * 32;
    const int b  = blockIdx.z;

    // ---- runtime layout probes (exact integer arithmetic in f64) ----
    f64x4 p1 = {0.0, 0.0, 0.0, 0.0};
    f64x4 p2 = {0.0, 0.0, 0.0, 0.0};
    const double lanev = (double)col;
    p1 = __builtin_amdgcn_mfma_f64_16x16x4f64(lanev, 1.0, p1, 0, 0, 0);
    p2 = __builtin_amdgcn_mfma_f64_16x16x4f64(1.0, lanev, p2, 0, 0, 0);
    int o_idx[4], n_idx[4];
#pragma unroll
    for (int r = 0; r < 4; ++r) {
        o_idx[r] = (int)(p1[r] * 0.25);   // which A-row (o within 16) reg r holds
        n_idx[r] = (int)(p2[r] * 0.25);   // which B-col (n within 16) reg r holds
    }

    f64x4 acc[2][2];                      // [mf][nf] for t = wave
#pragma unroll
    for (int mf = 0; mf < 2; ++mf)
#pragma unroll
        for (int nf = 0; nf < 2; ++nf)
            acc[mf][nf] = (f64x4){0.0, 0.0, 0.0, 0.0};

    for (int c0 = 0; c0 < CIN; c0 += 32) {
        // stage W tile: 32 o x 32 k  (256 float4, 1 per thread)
        {
            int ol = tid >> 3, k4 = tid & 7;
            float4 wv = *reinterpret_cast<const float4*>(
                &W[(size_t)(o0 + ol) * CIN + c0 + k4 * 4]);
            *reinterpret_cast<float4*>(&Ws[ol][k4 * 4]) = wv;
        }
        // stage X tiles for 4 timesteps: 4 x 32 k x 32 n (1024 float4, 4/thread)
        for (int idx = tid; idx < 1024; idx += 256) {
            int t = idx >> 8, kk = (idx >> 3) & 31, n4 = idx & 7;
            const size_t goff =
                (((size_t)t * BB + b) * CIN + c0 + kk) * NN + n0 + n4 * 4;
            float4 xv;
            if constexpr (__is_same(InT, uint8_t)) {
                uchar4 u = *reinterpret_cast<const uchar4*>(&X[goff]);
                xv = make_float4((float)u.x, (float)u.y, (float)u.z, (float)u.w);
            } else {
                xv = *reinterpret_cast<const float4*>(&X[goff]);
            }
            *reinterpret_cast<float4*>(&Xs[t][kk][n4 * 4]) = xv;
        }
        __syncthreads();
#pragma unroll
        for (int k0 = 0; k0 < 32; k0 += 4) {
            double av[2];
#pragma unroll
            for (int mf = 0; mf < 2; ++mf)
                av[mf] = (double)Ws[mf * 16 + col][k0 + rowg];
#pragma unroll
            for (int nf = 0; nf < 2; ++nf) {
                double bv = (double)Xs[wave][k0 + rowg][nf * 16 + col];
                acc[0][nf] = __builtin_amdgcn_mfma_f64_16x16x4f64(
                    av[0], bv, acc[0][nf], 0, 0, 0);
                acc[1][nf] = __builtin_amdgcn_mfma_f64_16x16x4f64(
                    av[1], bv, acc[1][nf], 0, 0, 0);
            }
        }
        __syncthreads();
    }

    // ---- epilogue: dump pre-activations to LDS (probe-indexed) ----
#pragma unroll
    for (int mf = 0; mf < 2; ++mf)
#pragma unroll
        for (int r = 0; r < 4; ++r)
#pragma unroll
            for (int nf = 0; nf < 2; ++nf)
                pre[((size_t)wave * 32 + mf * 16 + o_idx[r]) * 32
                    + nf * 16 + n_idx[r]] = acc[mf][nf][r];
    __syncthreads();

    // ---- BN + LIF (tau=2, hard reset, v_th=1): 4 outputs x 4 t per thread ----
    const int nl = tid & 31;
    const int obase = (tid >> 5) * 4;
#pragma unroll
    for (int i = 0; i < 4; ++i) {
        const int ol = obase + i;
        const int o  = o0 + ol;
        const double g   = (double)bn[0 * O + o];
        const double be  = (double)bn[1 * O + o];
        const double mu  = (double)bn[2 * O + o];
        const double var = (double)bn[3 * O + o];
        const double scale = g / sqrt(var + 1e-5);
        double bi = 0.0;
        if constexpr (HAS_BIAS) bi = (double)bias[o];
        double v = 0.0;
#pragma unroll
        for (int t = 0; t < TT; ++t) {
            double val = (pre[((size_t)t * 32 + ol) * 32 + nl] + bi - mu) * scale + be;
            v = v + (val - v) * 0.5;
            double s = (v >= 1.0) ? 1.0 : 0.0;
            size_t idx = (((size_t)t * BB + b) * O + o) * NN + n0 + nl;
            if constexpr (ADD_BASE) {
                Out[idx] = (OutT)((double)base[idx] + s);
            } else {
                Out[idx] = (OutT)s;
            }
            v = v * (1.0 - s);
        }
    }
}

// kv[t,b,h,d,e] = sum_n k[t,b,h*32+d,n] * v[t,b,h*32+e,n]  (exact int in fp32)
__global__ __launch_bounds__(256) void kv_kernel(
    const float* __restrict__ k_s, const float* __restrict__ v_s,
    float* __restrict__ kv)
{
    const int blk = blockIdx.x;          // (t*BB+b)*HEADS + h
    const int h = blk & 7;
    const int m = blk >> 3;              // t*BB + b
    __shared__ float ks[32][65];
    __shared__ float vs[32][65];
    const int tid = threadIdx.x;
    const int d = tid >> 3;
    const int e0 = (tid & 7) * 4;
    float acc[4] = {0.f, 0.f, 0.f, 0.f};
    const size_t basek = ((size_t)m * CC + h * DD) * NN;
    for (int nc = 0; nc < NN; nc += 64) {
        for (int i = tid; i < 2048; i += 256) {
            int r = i >> 6, nl = i & 63;
            ks[r][nl] = k_s[basek + (size_t)r * NN + nc + nl];
            vs[r][nl] = v_s[basek + (size_t)r * NN + nc + nl];
        }
        __syncthreads();
        for (int nl = 0; nl < 64; ++nl) {
            float kd = ks[d][nl];
#pragma unroll
            for (int j = 0; j < 4; ++j) acc[j] += kd * vs[e0 + j][nl];
        }
        __syncthreads();
    }
#pragma unroll
    for (int j = 0; j < 4; ++j)
        kv[(size_t)blk * 1024 + d * 32 + e0 + j] = acc[j];
}

// a = 0.125 * q @ kv -> LIF(v_th=0.5); exact dyadic arithmetic in fp32.
__global__ __launch_bounds__(256) void attn_a_lif(
    const float* __restrict__ q_s, const float* __restrict__ kv,
    float* __restrict__ a_s)
{
    const int tid = threadIdx.x;
    const int n = blockIdx.x * 256 + tid;
    const int c = blockIdx.y;
    const int b = blockIdx.z;
    const int h = c >> 5;
    const int e = c & 31;
    __shared__ float kvs[TT][32];
    if (tid < 128) {
        int t = tid >> 5, d2 = tid & 31;
        kvs[t][d2] = kv[(((size_t)t * BB + b) * HEADS + h) * 1024 + d2 * 32 + e];
    }
    __syncthreads();
    float val[TT];
#pragma unroll
    for (int t = 0; t < TT; ++t) {
        float s = 0.f;
        const size_t qb = (((size_t)t * BB + b) * CC + h * DD) * NN + n;
#pragma unroll 8
        for (int d2 = 0; d2 < 32; ++d2)
            s += q_s[qb + (size_t)d2 * NN] * kvs[t][d2];
        val[t] = s * 0.125f;
    }
    float v = 0.f;
#pragma unroll
    for (int t = 0; t < TT; ++t) {
        v = v + (val[t] - v) * 0.5f;
        float s = (v >= 0.5f) ? 1.f : 0.f;
        a_s[(((size_t)t * BB + b) * CC + c) * NN + n] = s;
        v = v * (1.f - s);
    }
}

extern "C" void kernel_launch(void* const* d_in, const int* in_sizes, int n_in,
                              void* d_out, int out_size, void* d_ws, size_t ws_size,
                              hipStream_t stream)
{
    const float* x       = (const float*)d_in[0];
    const float* q_w     = (const float*)d_in[1];
    const float* q_bn    = (const float*)d_in[2];
    const float* k_w     = (const float*)d_in[3];
    const float* k_bn    = (const float*)d_in[4];
    const float* v_w     = (const float*)d_in[5];
    const float* v_bn    = (const float*)d_in[6];
    const float* proj_w  = (const float*)d_in[7];
    const float* proj_b  = (const float*)d_in[8];
    const float* proj_bn = (const float*)d_in[9];
    const float* mlp1_w  = (const float*)d_in[10];
    const float* mlp1_b  = (const float*)d_in[11];
    const float* mlp1_bn = (const float*)d_in[12];
    const float* mlp2_w  = (const float*)d_in[13];
    const float* mlp2_b  = (const float*)d_in[14];
    const float* mlp2_bn = (const float*)d_in[15];

    const size_t SZ = (size_t)TT * BB * CC * NN;   // 8388608 elements
    char* ws = (char*)d_ws;
    float*   q_s   = (float*)(ws);
    float*   k_s   = (float*)(ws + SZ * 4);
    float*   v_s   = (float*)(ws + 2 * SZ * 4);
    float*   a_s   = (float*)(ws + 3 * SZ * 4);
    float*   kvb   = (float*)(ws + 4 * SZ * 4);    // 1 MB
    float*   x_new = (float*)(ws);                 // reuses q_s region
    uint8_t* h1    = (uint8_t*)(ws + SZ * 4);      // reuses k_s region (33.5 MB)

    dim3 blk(256);
    dim3 g256(NN / 32, 256 / 32, BB);    // (32, 8, 8)
    dim3 g1024(NN / 32, 1024 / 32, BB);  // (32, 32, 8)

    // Q/K/V conv + BN + LIF -> spike trains (f32 0/1)
    conv_bn_lif_mfma<float, float, false, false><<<g256, blk, 0, stream>>>(
        q_w, nullptr, q_bn, x, q_s, nullptr, 256, 256);
    conv_bn_lif_mfma<float, float, false, false><<<g256, blk, 0, stream>>>(
        k_w, nullptr, k_bn, x, k_s, nullptr, 256, 256);
    conv_bn_lif_mfma<float, float, false, false><<<g256, blk, 0, stream>>>(
        v_w, nullptr, v_bn, x, v_s, nullptr, 256, 256);

    // attention: kv = k^T v, then a = 0.125 * q kv -> LIF(0.5)
    kv_kernel<<<dim3(TT * BB * HEADS), blk, 0, stream>>>(k_s, v_s, kvb);
    attn_a_lif<<<dim3(4, 256, 8), blk, 0, stream>>>(q_s, kvb, a_s);

    // proj conv + bias + BN + LIF, fused residual: x_new = x + ssa
    conv_bn_lif_mfma<float, float, true, true><<<g256, blk, 0, stream>>>(
        proj_w, proj_b, proj_bn, a_s, x_new, x, 256, 256);

    // MLP: 256 -> 1024 (spikes as uint8) -> 256, fused residual to d_out
    conv_bn_lif_mfma<float, uint8_t, true, false><<<g1024, blk, 0, stream>>>(
        mlp1_w, mlp1_b, mlp1_bn, x_new, h1, nullptr, 1024, 256);
    conv_bn_lif_mfma<uint8_t, float, true, true><<<g256, blk, 0, stream>>>(
        mlp2_w, mlp2_b, mlp2_bn, h1, (float*)d_out, x_new, 256, 1024);
}

// Round 5
// 1048.371 us; speedup vs baseline: 2.3363x; 1.0530x over previous
//
#include <hip/hip_runtime.h>
#include <cstdint>
#include <cstddef>

#define TT 4
#define BB 8
#define CC 256
#define NN 1024
#define HEADS 8
#define DD 32

typedef __attribute__((ext_vector_type(4))) double f64x4;

// Fused conv1x1 (GEMM) + BatchNorm + LIF-over-time using fp64 MFMA.
// Block: 32(o) x 32(n) tile, 4 waves; wave w computes timestep t=w.
// Double-buffered LDS with register staging (issue-early / write-late):
// one barrier per K-step; global-load latency hides under the MFMA phase.
// LIF runs in an LDS epilogue; C/D lane mapping of v_mfma_f64_16x16x4f64
// recovered at runtime via two probe MFMAs (layout-agnostic).
template<typename InT, typename OutT, bool HAS_BIAS, bool ADD_BASE>
__global__ __launch_bounds__(256, 3) void conv_bn_lif_mfma(
    const float* __restrict__ W,      // [O, CIN]
    const float* __restrict__ bias,   // [O] or null
    const float* __restrict__ bn,     // [4, O] gamma,beta,mean,var
    const InT*   __restrict__ X,      // [T, B, CIN, N]
    OutT*        __restrict__ Out,    // [T, B, O, N]
    const float* __restrict__ base,   // [T, B, O, N] (ADD_BASE) or null
    int O, int CIN)
{
    __shared__ __align__(16) float Ws[2][32][36];      // 9216 B
    __shared__ __align__(16) float Xs[2][TT][32][40];  // 40960 B
    double* pre = (double*)&Xs[0][0][0][0];            // [4][32][32] f64 overlay (32 KB)

    const int tid  = threadIdx.x;
    const int lane = tid & 63;
    const int wave = tid >> 6;          // == timestep t for the GEMM phase
    const int col  = lane & 15;
    const int rowg = lane >> 4;         // 0..3  (k-group)
    const int n0 = blockIdx.x * 32;
    const int o0 = blockIdx.y * 32;
    const int b  = blockIdx.z;

    // staging thread mapping (fixed across iterations)
    const int w_ol = tid >> 3, w_k4 = tid & 7;      // W: [32 o][8 k4]
    const int x_kk = tid >> 3, x_n4 = tid & 7;      // X: [32 k][8 n4] per t

    // ---- runtime layout probes (exact integer arithmetic in f64) ----
    f64x4 p1 = {0.0, 0.0, 0.0, 0.0};
    f64x4 p2 = {0.0, 0.0, 0.0, 0.0};
    const double lanev = (double)col;
    p1 = __builtin_amdgcn_mfma_f64_16x16x4f64(lanev, 1.0, p1, 0, 0, 0);
    p2 = __builtin_amdgcn_mfma_f64_16x16x4f64(1.0, lanev, p2, 0, 0, 0);
    int o_idx[4], n_idx[4];
#pragma unroll
    for (int r = 0; r < 4; ++r) {
        o_idx[r] = (int)(p1[r] * 0.25);   // which A-row (o within 16) reg r holds
        n_idx[r] = (int)(p2[r] * 0.25);   // which B-col (n within 16) reg r holds
    }

    f64x4 acc[2][2];                      // [mf][nf] for t = wave
#pragma unroll
    for (int mf = 0; mf < 2; ++mf)
#pragma unroll
        for (int nf = 0; nf < 2; ++nf)
            acc[mf][nf] = (f64x4){0.0, 0.0, 0.0, 0.0};

    // in-flight staging registers
    float4 rW;
    float4 rX[TT];
    uchar4 rXu[TT];

    auto issue_loads = [&](int c0) {
        rW = *reinterpret_cast<const float4*>(
            &W[(size_t)(o0 + w_ol) * CIN + c0 + w_k4 * 4]);
#pragma unroll
        for (int j = 0; j < TT; ++j) {
            const size_t goff =
                (((size_t)j * BB + b) * CIN + c0 + x_kk) * NN + n0 + x_n4 * 4;
            if constexpr (__is_same(InT, uint8_t)) {
                rXu[j] = *reinterpret_cast<const uchar4*>(&X[goff]);
            } else {
                rX[j] = *reinterpret_cast<const float4*>(&X[goff]);
            }
        }
    };
    auto write_tiles = [&](int buf) {
        *reinterpret_cast<float4*>(&Ws[buf][w_ol][w_k4 * 4]) = rW;
#pragma unroll
        for (int j = 0; j < TT; ++j) {
            float4 xv;
            if constexpr (__is_same(InT, uint8_t)) {
                xv = make_float4((float)rXu[j].x, (float)rXu[j].y,
                                 (float)rXu[j].z, (float)rXu[j].w);
            } else {
                xv = rX[j];
            }
            *reinterpret_cast<float4*>(&Xs[buf][j][x_kk][x_n4 * 4]) = xv;
        }
    };

    // prologue: stage tile 0
    issue_loads(0);
    write_tiles(0);
    __syncthreads();

    int cur = 0;
    for (int c0 = 32; c0 <= CIN; c0 += 32) {
        const bool has_next = (c0 < CIN);
        if (has_next) issue_loads(c0);          // issue-early (hidden under MFMA)
#pragma unroll
        for (int k0 = 0; k0 < 32; k0 += 4) {
            double av[2];
#pragma unroll
            for (int mf = 0; mf < 2; ++mf)
                av[mf] = (double)Ws[cur][mf * 16 + col][k0 + rowg];
#pragma unroll
            for (int nf = 0; nf < 2; ++nf) {
                double bv = (double)Xs[cur][wave][k0 + rowg][nf * 16 + col];
                acc[0][nf] = __builtin_amdgcn_mfma_f64_16x16x4f64(
                    av[0], bv, acc[0][nf], 0, 0, 0);
                acc[1][nf] = __builtin_amdgcn_mfma_f64_16x16x4f64(
                    av[1], bv, acc[1][nf], 0, 0, 0);
            }
        }
        if (has_next) write_tiles(cur ^ 1);     // write-late (after vmcnt wait)
        __syncthreads();                        // single barrier per K-step
        cur ^= 1;
    }

    // ---- epilogue: dump pre-activations to LDS (probe-indexed) ----
#pragma unroll
    for (int mf = 0; mf < 2; ++mf)
#pragma unroll
        for (int r = 0; r < 4; ++r)
#pragma unroll
            for (int nf = 0; nf < 2; ++nf)
                pre[((size_t)wave * 32 + mf * 16 + o_idx[r]) * 32
                    + nf * 16 + n_idx[r]] = acc[mf][nf][r];
    __syncthreads();

    // ---- BN + LIF (tau=2, hard reset, v_th=1): 4 outputs x 4 t per thread ----
    const int nl = tid & 31;
    const int obase = (tid >> 5) * 4;
#pragma unroll
    for (int i = 0; i < 4; ++i) {
        const int ol = obase + i;
        const int o  = o0 + ol;
        const double g   = (double)bn[0 * O + o];
        const double be  = (double)bn[1 * O + o];
        const double mu  = (double)bn[2 * O + o];
        const double var = (double)bn[3 * O + o];
        const double scale = g / sqrt(var + 1e-5);
        double bi = 0.0;
        if constexpr (HAS_BIAS) bi = (double)bias[o];
        double v = 0.0;
#pragma unroll
        for (int t = 0; t < TT; ++t) {
            double val = (pre[((size_t)t * 32 + ol) * 32 + nl] + bi - mu) * scale + be;
            v = v + (val - v) * 0.5;
            double s = (v >= 1.0) ? 1.0 : 0.0;
            size_t idx = (((size_t)t * BB + b) * O + o) * NN + n0 + nl;
            if constexpr (ADD_BASE) {
                Out[idx] = (OutT)((double)base[idx] + s);
            } else {
                Out[idx] = (OutT)s;
            }
            v = v * (1.0 - s);
        }
    }
}

// kv[t,b,h,d,e] = sum_n k[t,b,h*32+d,n] * v[t,b,h*32+e,n]  (exact int in fp32)
__global__ __launch_bounds__(256) void kv_kernel(
    const float* __restrict__ k_s, const float* __restrict__ v_s,
    float* __restrict__ kv)
{
    const int blk = blockIdx.x;          // (t*BB+b)*HEADS + h
    const int h = blk & 7;
    const int m = blk >> 3;              // t*BB + b
    __shared__ float ks[32][65];
    __shared__ float vs[32][65];
    const int tid = threadIdx.x;
    const int d = tid >> 3;
    const int e0 = (tid & 7) * 4;
    float acc[4] = {0.f, 0.f, 0.f, 0.f};
    const size_t basek = ((size_t)m * CC + h * DD) * NN;
    for (int nc = 0; nc < NN; nc += 64) {
        for (int i = tid; i < 2048; i += 256) {
            int r = i >> 6, nl = i & 63;
            ks[r][nl] = k_s[basek + (size_t)r * NN + nc + nl];
            vs[r][nl] = v_s[basek + (size_t)r * NN + nc + nl];
        }
        __syncthreads();
        for (int nl = 0; nl < 64; ++nl) {
            float kd = ks[d][nl];
#pragma unroll
            for (int j = 0; j < 4; ++j) acc[j] += kd * vs[e0 + j][nl];
        }
        __syncthreads();
    }
#pragma unroll
    for (int j = 0; j < 4; ++j)
        kv[(size_t)blk * 1024 + d * 32 + e0 + j] = acc[j];
}

// a = 0.125 * q @ kv -> LIF(v_th=0.5); exact dyadic arithmetic in fp32.
__global__ __launch_bounds__(256) void attn_a_lif(
    const float* __restrict__ q_s, const float* __restrict__ kv,
    float* __restrict__ a_s)
{
    const int tid = threadIdx.x;
    const int n = blockIdx.x * 256 + tid;
    const int c = blockIdx.y;
    const int b = blockIdx.z;
    const int h = c >> 5;
    const int e = c & 31;
    __shared__ float kvs[TT][32];
    if (tid < 128) {
        int t = tid >> 5, d2 = tid & 31;
        kvs[t][d2] = kv[(((size_t)t * BB + b) * HEADS + h) * 1024 + d2 * 32 + e];
    }
    __syncthreads();
    float val[TT];
#pragma unroll
    for (int t = 0; t < TT; ++t) {
        float s = 0.f;
        const size_t qb = (((size_t)t * BB + b) * CC + h * DD) * NN + n;
#pragma unroll 8
        for (int d2 = 0; d2 < 32; ++d2)
            s += q_s[qb + (size_t)d2 * NN] * kvs[t][d2];
        val[t] = s * 0.125f;
    }
    float v = 0.f;
#pragma unroll
    for (int t = 0; t < TT; ++t) {
        v = v + (val[t] - v) * 0.5f;
        float s = (v >= 0.5f) ? 1.f : 0.f;
        a_s[(((size_t)t * BB + b) * CC + c) * NN + n] = s;
        v = v * (1.f - s);
    }
}

extern "C" void kernel_launch(void* const* d_in, const int* in_sizes, int n_in,
                              void* d_out, int out_size, void* d_ws, size_t ws_size,
                              hipStream_t stream)
{
    const float* x       = (const float*)d_in[0];
    const float* q_w     = (const float*)d_in[1];
    const float* q_bn    = (const float*)d_in[2];
    const float* k_w     = (const float*)d_in[3];
    const float* k_bn    = (const float*)d_in[4];
    const float* v_w     = (const float*)d_in[5];
    const float* v_bn    = (const float*)d_in[6];
    const float* proj_w  = (const float*)d_in[7];
    const float* proj_b  = (const float*)d_in[8];
    const float* proj_bn = (const float*)d_in[9];
    const float* mlp1_w  = (const float*)d_in[10];
    const float* mlp1_b  = (const float*)d_in[11];
    const float* mlp1_bn = (const float*)d_in[12];
    const float* mlp2_w  = (const float*)d_in[13];
    const float* mlp2_b  = (const float*)d_in[14];
    const float* mlp2_bn = (const float*)d_in[15];

    const size_t SZ = (size_t)TT * BB * CC * NN;   // 8388608 elements
    char* ws = (char*)d_ws;
    float*   q_s   = (float*)(ws);
    float*   k_s   = (float*)(ws + SZ * 4);
    float*   v_s   = (float*)(ws + 2 * SZ * 4);
    float*   a_s   = (float*)(ws + 3 * SZ * 4);
    float*   kvb   = (float*)(ws + 4 * SZ * 4);    // 1 MB
    float*   x_new = (float*)(ws);                 // reuses q_s region
    uint8_t* h1    = (uint8_t*)(ws + SZ * 4);      // reuses k_s region (33.5 MB)

    dim3 blk(256);
    dim3 g256(NN / 32, 256 / 32, BB);    // (32, 8, 8)
    dim3 g1024(NN / 32, 1024 / 32, BB);  // (32, 32, 8)

    // Q/K/V conv + BN + LIF -> spike trains (f32 0/1)
    conv_bn_lif_mfma<float, float, false, false><<<g256, blk, 0, stream>>>(
        q_w, nullptr, q_bn, x, q_s, nullptr, 256, 256);
    conv_bn_lif_mfma<float, float, false, false><<<g256, blk, 0, stream>>>(
        k_w, nullptr, k_bn, x, k_s, nullptr, 256, 256);
    conv_bn_lif_mfma<float, float, false, false><<<g256, blk, 0, stream>>>(
        v_w, nullptr, v_bn, x, v_s, nullptr, 256, 256);

    // attention: kv = k^T v, then a = 0.125 * q kv -> LIF(0.5)
    kv_kernel<<<dim3(TT * BB * HEADS), blk, 0, stream>>>(k_s, v_s, kvb);
    attn_a_lif<<<dim3(4, 256, 8), blk, 0, stream>>>(q_s, kvb, a_s);

    // proj conv + bias + BN + LIF, fused residual: x_new = x + ssa
    conv_bn_lif_mfma<float, float, true, true><<<g256, blk, 0, stream>>>(
        proj_w, proj_b, proj_bn, a_s, x_new, x, 256, 256);

    // MLP: 256 -> 1024 (spikes as uint8) -> 256, fused residual to d_out
    conv_bn_lif_mfma<float, uint8_t, true, false><<<g1024, blk, 0, stream>>>(
        mlp1_w, mlp1_b, mlp1_bn, x_new, h1, nullptr, 1024, 256);
    conv_bn_lif_mfma<uint8_t, float, true, true><<<g256, blk, 0, stream>>>(
        mlp2_w, mlp2_b, mlp2_bn, h1, (float*)d_out, x_new, 256, 1024);
}

// Round 6
// 1040.924 us; speedup vs baseline: 2.3530x; 1.0072x over previous
//
#include <hip/hip_runtime.h>
#include <cstdint>
#include <cstddef>

#define TT 4
#define BB 8
#define CC 256
#define NN 1024
#define HEADS 8
#define DD 32

typedef __attribute__((ext_vector_type(4))) double f64x4;

// Fused conv1x1 (GEMM) + BatchNorm + LIF-over-time using fp64 MFMA.
// Block: 32(o) x 32(n) tile, 4 waves; wave w computes timestep t=w.
// LDS = 40960 B exactly -> 4 blocks/CU. Un-padded tiles with additive
// column-rotate swizzle col' = (c + 8*(k&3)) & 31 (reads 2-way = free);
// W stored transposed [k][o] so A/B reads share per-thread column consts.
// Double-buffered reg-staging (issue-early/write-late), 1 barrier/K-step.
// C/D mapping of v_mfma_f64_16x16x4f64 recovered at runtime via probes.
template<typename InT, typename OutT, bool HAS_BIAS, bool ADD_BASE, bool TRIPLE>
__global__ __launch_bounds__(256, 4) void conv_bn_lif_mfma(
    const float* __restrict__ W0, const float* __restrict__ W1,
    const float* __restrict__ W2, const float* __restrict__ bias,
    const float* __restrict__ bn0, const float* __restrict__ bn1,
    const float* __restrict__ bn2,
    const InT* __restrict__ X,
    OutT* __restrict__ Out0, OutT* __restrict__ Out1, OutT* __restrict__ Out2,
    const float* __restrict__ base,   // [T, B, O, N] (ADD_BASE) or null
    int O, int CIN)
{
    __shared__ __align__(16) float Ws[2][32][32];      // [buf][k][o] swizzled, 8192 B
    __shared__ __align__(16) float Xs[2][TT][32][32];  // [buf][t][k][c] swizzled, 32768 B
    double* pre = (double*)&Xs[0][0][0][0];            // [4][32][32] f64 overlay (32 KB)

    const int tid  = threadIdx.x;
    const int lane = tid & 63;
    const int wave = tid >> 6;          // == timestep t for the GEMM phase
    const int col  = lane & 15;
    const int rowg = lane >> 4;         // 0..3  (k-group)
    const int n0 = blockIdx.x * 32;
    const int b  = blockIdx.z;

    int o0;
    const float *W, *bn;
    OutT* Out;
    if constexpr (TRIPLE) {
        const int sel = blockIdx.y >> 3;
        o0 = (blockIdx.y & 7) * 32;
        W   = sel == 0 ? W0  : (sel == 1 ? W1  : W2);
        bn  = sel == 0 ? bn0 : (sel == 1 ? bn1 : bn2);
        Out = sel == 0 ? Out0 : (sel == 1 ? Out1 : Out2);
    } else {
        o0 = blockIdx.y * 32;
        W = W0; bn = bn0; Out = Out0;
    }

    // staging thread mapping (fixed across iterations)
    const int w_ol = tid >> 3, w_k4 = tid & 7;      // W: [32 o][8 k4]
    const int x_kk = tid >> 3, x_n4 = tid & 7;      // X: [32 k][8 n4] per t
    const int xsw  = (x_n4 * 4 + 8 * (x_kk & 3)) & 31;  // swizzled col for X write

    // per-thread swizzled read columns (same for W^T and X)
    const int cb0 = (col + 8 * rowg) & 31;
    const int cb1 = (col + 16 + 8 * rowg) & 31;

    // ---- runtime layout probes (exact integer arithmetic in f64) ----
    f64x4 p1 = {0.0, 0.0, 0.0, 0.0};
    f64x4 p2 = {0.0, 0.0, 0.0, 0.0};
    const double lanev = (double)col;
    p1 = __builtin_amdgcn_mfma_f64_16x16x4f64(lanev, 1.0, p1, 0, 0, 0);
    p2 = __builtin_amdgcn_mfma_f64_16x16x4f64(1.0, lanev, p2, 0, 0, 0);
    int o_idx[4], n_idx[4];
#pragma unroll
    for (int r = 0; r < 4; ++r) {
        o_idx[r] = (int)(p1[r] * 0.25);   // which A-row (o within 16) reg r holds
        n_idx[r] = (int)(p2[r] * 0.25);   // which B-col (n within 16) reg r holds
    }

    f64x4 acc[2][2];                      // [mf][nf] for t = wave
#pragma unroll
    for (int mf = 0; mf < 2; ++mf)
#pragma unroll
        for (int nf = 0; nf < 2; ++nf)
            acc[mf][nf] = (f64x4){0.0, 0.0, 0.0, 0.0};

    // in-flight staging registers
    float4 rW;
    float4 rX[TT];
    uchar4 rXu[TT];

    auto issue_loads = [&](int c0) {
        rW = *reinterpret_cast<const float4*>(
            &W[(size_t)(o0 + w_ol) * CIN + c0 + w_k4 * 4]);
#pragma unroll
        for (int j = 0; j < TT; ++j) {
            const size_t goff =
                (((size_t)j * BB + b) * CIN + c0 + x_kk) * NN + n0 + x_n4 * 4;
            if constexpr (__is_same(InT, uint8_t)) {
                rXu[j] = *reinterpret_cast<const uchar4*>(&X[goff]);
            } else {
                rX[j] = *reinterpret_cast<const float4*>(&X[goff]);
            }
        }
    };
    auto write_tiles = [&](int buf) {
        // W transposed + swizzled: element (k, o) -> Ws[k][(o + 8*(k&3))&31]
        Ws[buf][w_k4 * 4 + 0][(w_ol + 0 ) & 31] = rW.x;
        Ws[buf][w_k4 * 4 + 1][(w_ol + 8 ) & 31] = rW.y;
        Ws[buf][w_k4 * 4 + 2][(w_ol + 16) & 31] = rW.z;
        Ws[buf][w_k4 * 4 + 3][(w_ol + 24) & 31] = rW.w;
#pragma unroll
        for (int j = 0; j < TT; ++j) {
            float4 xv;
            if constexpr (__is_same(InT, uint8_t)) {
                xv = make_float4((float)rXu[j].x, (float)rXu[j].y,
                                 (float)rXu[j].z, (float)rXu[j].w);
            } else {
                xv = rX[j];
            }
            *reinterpret_cast<float4*>(&Xs[buf][j][x_kk][xsw]) = xv;
        }
    };

    // prologue: stage tile 0
    issue_loads(0);
    write_tiles(0);
    __syncthreads();

    int cur = 0;
    for (int c0 = 32; c0 <= CIN; c0 += 32) {
        const bool has_next = (c0 < CIN);
        if (has_next) issue_loads(c0);          // issue-early (hidden under MFMA)
#pragma unroll
        for (int k0 = 0; k0 < 32; k0 += 4) {
            const int kr = k0 + rowg;
            double av0 = (double)Ws[cur][kr][cb0];
            double av1 = (double)Ws[cur][kr][cb1];
            double bv0 = (double)Xs[cur][wave][kr][cb0];
            double bv1 = (double)Xs[cur][wave][kr][cb1];
            acc[0][0] = __builtin_amdgcn_mfma_f64_16x16x4f64(av0, bv0, acc[0][0], 0, 0, 0);
            acc[1][0] = __builtin_amdgcn_mfma_f64_16x16x4f64(av1, bv0, acc[1][0], 0, 0, 0);
            acc[0][1] = __builtin_amdgcn_mfma_f64_16x16x4f64(av0, bv1, acc[0][1], 0, 0, 0);
            acc[1][1] = __builtin_amdgcn_mfma_f64_16x16x4f64(av1, bv1, acc[1][1], 0, 0, 0);
        }
        if (has_next) write_tiles(cur ^ 1);     // write-late
        __syncthreads();                        // single barrier per K-step
        cur ^= 1;
    }

    // ---- epilogue: dump pre-activations to LDS (probe-indexed) ----
#pragma unroll
    for (int mf = 0; mf < 2; ++mf)
#pragma unroll
        for (int r = 0; r < 4; ++r)
#pragma unroll
            for (int nf = 0; nf < 2; ++nf)
                pre[((size_t)wave * 32 + mf * 16 + o_idx[r]) * 32
                    + nf * 16 + n_idx[r]] = acc[mf][nf][r];
    __syncthreads();

    // ---- BN + LIF (tau=2, hard reset, v_th=1): 4 outputs x 4 t per thread ----
    const int nl = tid & 31;
    const int obase = (tid >> 5) * 4;
#pragma unroll
    for (int i = 0; i < 4; ++i) {
        const int ol = obase + i;
        const int o  = o0 + ol;
        const double g   = (double)bn[0 * O + o];
        const double be  = (double)bn[1 * O + o];
        const double mu  = (double)bn[2 * O + o];
        const double var = (double)bn[3 * O + o];
        const double scale = g / sqrt(var + 1e-5);
        double bi = 0.0;
        if constexpr (HAS_BIAS) bi = (double)bias[o];
        double v = 0.0;
#pragma unroll
        for (int t = 0; t < TT; ++t) {
            double val = (pre[((size_t)t * 32 + ol) * 32 + nl] + bi - mu) * scale + be;
            v = v + (val - v) * 0.5;
            double s = (v >= 1.0) ? 1.0 : 0.0;
            size_t idx = (((size_t)t * BB + b) * O + o) * NN + n0 + nl;
            if constexpr (ADD_BASE) {
                Out[idx] = (OutT)((double)base[idx] + s);
            } else {
                Out[idx] = (OutT)s;
            }
            v = v * (1.0 - s);
        }
    }
}

// kv[t,b,h,d,e] = sum_n k[t,b,h*32+d,n] * v[t,b,h*32+e,n]  (exact int in fp32)
__global__ __launch_bounds__(256) void kv_kernel(
    const float* __restrict__ k_s, const float* __restrict__ v_s,
    float* __restrict__ kv)
{
    const int blk = blockIdx.x;          // (t*BB+b)*HEADS + h
    const int h = blk & 7;
    const int m = blk >> 3;              // t*BB + b
    __shared__ float ks[32][65];
    __shared__ float vs[32][65];
    const int tid = threadIdx.x;
    const int d = tid >> 3;
    const int e0 = (tid & 7) * 4;
    float acc[4] = {0.f, 0.f, 0.f, 0.f};
    const size_t basek = ((size_t)m * CC + h * DD) * NN;
    for (int nc = 0; nc < NN; nc += 64) {
        for (int i = tid; i < 2048; i += 256) {
            int r = i >> 6, nl = i & 63;
            ks[r][nl] = k_s[basek + (size_t)r * NN + nc + nl];
            vs[r][nl] = v_s[basek + (size_t)r * NN + nc + nl];
        }
        __syncthreads();
        for (int nl = 0; nl < 64; ++nl) {
            float kd = ks[d][nl];
#pragma unroll
            for (int j = 0; j < 4; ++j) acc[j] += kd * vs[e0 + j][nl];
        }
        __syncthreads();
    }
#pragma unroll
    for (int j = 0; j < 4; ++j)
        kv[(size_t)blk * 1024 + d * 32 + e0 + j] = acc[j];
}

// a = 0.125 * q @ kv -> LIF(v_th=0.5); exact dyadic arithmetic in fp32.
__global__ __launch_bounds__(256) void attn_a_lif(
    const float* __restrict__ q_s, const float* __restrict__ kv,
    float* __restrict__ a_s)
{
    const int tid = threadIdx.x;
    const int n = blockIdx.x * 256 + tid;
    const int c = blockIdx.y;
    const int b = blockIdx.z;
    const int h = c >> 5;
    const int e = c & 31;
    __shared__ float kvs[TT][32];
    if (tid < 128) {
        int t = tid >> 5, d2 = tid & 31;
        kvs[t][d2] = kv[(((size_t)t * BB + b) * HEADS + h) * 1024 + d2 * 32 + e];
    }
    __syncthreads();
    float val[TT];
#pragma unroll
    for (int t = 0; t < TT; ++t) {
        float s = 0.f;
        const size_t qb = (((size_t)t * BB + b) * CC + h * DD) * NN + n;
#pragma unroll 8
        for (int d2 = 0; d2 < 32; ++d2)
            s += q_s[qb + (size_t)d2 * NN] * kvs[t][d2];
        val[t] = s * 0.125f;
    }
    float v = 0.f;
#pragma unroll
    for (int t = 0; t < TT; ++t) {
        v = v + (val[t] - v) * 0.5f;
        float s = (v >= 0.5f) ? 1.f : 0.f;
        a_s[(((size_t)t * BB + b) * CC + c) * NN + n] = s;
        v = v * (1.f - s);
    }
}

extern "C" void kernel_launch(void* const* d_in, const int* in_sizes, int n_in,
                              void* d_out, int out_size, void* d_ws, size_t ws_size,
                              hipStream_t stream)
{
    const float* x       = (const float*)d_in[0];
    const float* q_w     = (const float*)d_in[1];
    const float* q_bn    = (const float*)d_in[2];
    const float* k_w     = (const float*)d_in[3];
    const float* k_bn    = (const float*)d_in[4];
    const float* v_w     = (const float*)d_in[5];
    const float* v_bn    = (const float*)d_in[6];
    const float* proj_w  = (const float*)d_in[7];
    const float* proj_b  = (const float*)d_in[8];
    const float* proj_bn = (const float*)d_in[9];
    const float* mlp1_w  = (const float*)d_in[10];
    const float* mlp1_b  = (const float*)d_in[11];
    const float* mlp1_bn = (const float*)d_in[12];
    const float* mlp2_w  = (const float*)d_in[13];
    const float* mlp2_b  = (const float*)d_in[14];
    const float* mlp2_bn = (const float*)d_in[15];

    const size_t SZ = (size_t)TT * BB * CC * NN;   // 8388608 elements
    char* ws = (char*)d_ws;
    float*   q_s   = (float*)(ws);
    float*   k_s   = (float*)(ws + SZ * 4);
    float*   v_s   = (float*)(ws + 2 * SZ * 4);
    float*   a_s   = (float*)(ws + 3 * SZ * 4);
    float*   kvb   = (float*)(ws + 4 * SZ * 4);    // 1 MB
    float*   x_new = (float*)(ws);                 // reuses q_s region
    uint8_t* h1    = (uint8_t*)(ws + SZ * 4);      // reuses k_s region (33.5 MB)

    dim3 blk(256);
    dim3 gqkv(NN / 32, 3 * 256 / 32, BB);  // (32, 24, 8) fused q/k/v
    dim3 g256(NN / 32, 256 / 32, BB);      // (32, 8, 8)
    dim3 g1024(NN / 32, 1024 / 32, BB);    // (32, 32, 8)

    // Q/K/V conv + BN + LIF -> spike trains (f32 0/1), one fused dispatch
    conv_bn_lif_mfma<float, float, false, false, true><<<gqkv, blk, 0, stream>>>(
        q_w, k_w, v_w, nullptr, q_bn, k_bn, v_bn, x, q_s, k_s, v_s,
        nullptr, 256, 256);

    // attention: kv = k^T v, then a = 0.125 * q kv -> LIF(0.5)
    kv_kernel<<<dim3(TT * BB * HEADS), blk, 0, stream>>>(k_s, v_s, kvb);
    attn_a_lif<<<dim3(4, 256, 8), blk, 0, stream>>>(q_s, kvb, a_s);

    // proj conv + bias + BN + LIF, fused residual: x_new = x + ssa
    conv_bn_lif_mfma<float, float, true, true, false><<<g256, blk, 0, stream>>>(
        proj_w, nullptr, nullptr, proj_b, proj_bn, nullptr, nullptr, a_s,
        x_new, nullptr, nullptr, x, 256, 256);

    // MLP: 256 -> 1024 (spikes as uint8) -> 256, fused residual to d_out
    conv_bn_lif_mfma<float, uint8_t, true, false, false><<<g1024, blk, 0, stream>>>(
        mlp1_w, nullptr, nullptr, mlp1_b, mlp1_bn, nullptr, nullptr, x_new,
        h1, nullptr, nullptr, nullptr, 1024, 256);
    conv_bn_lif_mfma<uint8_t, float, true, true, false><<<g256, blk, 0, stream>>>(
        mlp2_w, nullptr, nullptr, mlp2_b, mlp2_bn, nullptr, nullptr, h1,
        (float*)d_out, nullptr, nullptr, x_new, 256, 1024);
}